// Round 2
// baseline (305.734 us; speedup 1.0000x reference)
//
#include <hip/hip_runtime.h>

// z_{t+1} = z_t @ K, T=256, B=256, D=512. out[b,t,d] = (z0 @ K^{t+1})[b,d], fp32.
//
// Chunked matrix powers, c=16 (ladder depth 9, bf16x3 split precision), then a
// fully parallel phase: out[16j+i-1] = w_j @ K^i (plain bf16, 2048 WGs).
//
// ALL intermediates are stored in MFMA-fragment-packed layout: 1KB chunks where
// chunk (r>>4, k>>5) holds the exact bytes the 64 lanes of a 16x16x32 fragment
// read (elem = chunk*512 + lane*8 + j, lane = (r&15) | ((k>>3)&3)<<4).
//  -> A-operand fragments load DIRECTLY from global (coalesced dwordx4, no LDS)
//  -> B staging is one gll16 per chunk, LDS reads are base+lane*16: conflict-free
// Slot layout (u16): [Apk-hi | Apk-lo | Bpk-hi | Bpk-lo], Bpk(M) = Apk(M^T).

typedef unsigned short u16;
typedef unsigned int u32;
typedef __bf16 bf16x8 __attribute__((ext_vector_type(8)));
typedef float f32x4 __attribute__((ext_vector_type(4)));

#define MAT 262144    /* 512*512 elems */
#define SLOT 1048576  /* 4*MAT u16 per power slot */
#define WSLOT 131072  /* 256*512 */

__device__ __forceinline__ u16 f2b(float f) {  // fp32 -> bf16 (RNE)
  u32 x = __float_as_uint(f);
  return (u16)((x + 0x7fffu + ((x >> 16) & 1u)) >> 16);
}
__device__ __forceinline__ float b2f(u16 u) { return __uint_as_float(((u32)u) << 16); }

// fragment-packed index for element (r, k), K-dim = 512
__device__ __forceinline__ size_t pidx(int r, int k) {
  return (size_t)(((r >> 4) * 16 + (k >> 5)) * 512 + ((k >> 3) & 3) * 128 + (r & 15) * 8 + (k & 7));
}

__device__ __forceinline__ void gll16(const void* g, void* l) {
  __builtin_amdgcn_global_load_lds((__attribute__((address_space(1))) void*)(void*)g,
                                   (__attribute__((address_space(3))) void*)l, 16, 0, 0);
}

// ---- prep: pack K into slot0 (4 forms); split z0 -> W0(Apk-hi) + z0lo(Apk-lo) ----
__global__ __launch_bounds__(256) void prep_kernel(const float* __restrict__ Kc,
                                                   const float* __restrict__ z0,
                                                   u16* __restrict__ P,
                                                   u16* __restrict__ W0,
                                                   u16* __restrict__ z0lo) {
  int tid = threadIdx.x, b = blockIdx.x;
  if (b < 64) {
    int r0 = (b >> 3) * 64, c0 = (b & 7) * 64;
#pragma unroll 4
    for (int q = 0; q < 16; ++q) {
      int lin = q * 256 + tid;
      int r = r0 + (lin >> 6), c = c0 + (lin & 63);
      float v = Kc[(size_t)r * 512 + c];
      u16 h = f2b(v), l = f2b(v - b2f(h));
      size_t ia = pidx(r, c), ib = pidx(c, r);
      P[ia] = h;
      P[MAT + ia] = l;
      P[2 * MAT + ib] = h;
      P[3 * MAT + ib] = l;
    }
  } else {
    int idb = b - 64;  // 32 blocks cover 131072 elems
#pragma unroll 4
    for (int q = 0; q < 16; ++q) {
      int id = (idb * 16 + q) * 256 + tid;
      int r = id >> 9, c = id & 511;
      float v = z0[id];
      u16 h = f2b(v);
      size_t ia = pidx(r, c);
      W0[ia] = h;
      z0lo[ia] = f2b(v - b2f(h));
    }
  }
}

// ---- ladder GEMM: C[M,512] = A @ B, bf16x3. 64x64 tile, KB=128 groups.
// A hi/lo read direct from global (packed); B hi/lo staged via gll16.
// wmode 0: write full 4-form slot; wmode 1: Apk-hi only (W slot).
__global__ __launch_bounds__(256, 1) void gemm_split(
    const u16* __restrict__ A0h, const u16* __restrict__ A0l, long Astr,
    const u16* __restrict__ B0h, long Bstr,
    u16* __restrict__ C0, long Cstr, int wmode) {
  __shared__ u16 Bs[2][16 * 512];  // [hi/lo][kt4 x nt4 chunks] = 32KB
  int z = blockIdx.z;
  const u16* Ah = A0h + (size_t)z * Astr;
  const u16* Al = A0l + (size_t)z * Astr;
  const u16* Bh = B0h + (size_t)z * Bstr;
  const u16* Bl = Bh + MAT;
  u16* C = C0 + (size_t)z * Cstr;
  int tid = threadIdx.x;
  int m0 = blockIdx.y * 64, n0 = blockIdx.x * 64;
  int wv = tid >> 6, lane = tid & 63;
  int wm = wv >> 1, wn = wv & 1, mrow = lane & 15, quad = lane >> 4;
  int l8 = lane * 8;
  int mchunk0 = (m0 >> 4) + wm * 2;
  int nchunk0 = n0 >> 4;
  f32x4 acc[2][2] = {};
  for (int g = 0; g < 4; ++g) {
    // stage 32 B chunks (hi+lo), 8 per wave
#pragma unroll
    for (int i = 0; i < 8; ++i) {
      int id = wv * 8 + i;  // 0..31
      int hl = id >> 4, kt_f = (id >> 2) & 3, nt_loc = id & 3;
      const u16* src = (hl ? Bl : Bh) + (size_t)((nchunk0 + nt_loc) * 16 + g * 4 + kt_f) * 512 + l8;
      gll16(src, &Bs[hl][(kt_f * 4 + nt_loc) * 512]);
    }
    __syncthreads();
#pragma unroll
    for (int kt_f = 0; kt_f < 4; ++kt_f) {
      int kt = g * 4 + kt_f;
      bf16x8 ah[2], al[2], bh[2], bl[2];
#pragma unroll
      for (int mt = 0; mt < 2; ++mt) {
        size_t co = (size_t)((mchunk0 + mt) * 16 + kt) * 512 + l8;
        ah[mt] = *(const bf16x8*)(Ah + co);
        al[mt] = *(const bf16x8*)(Al + co);
      }
#pragma unroll
      for (int nt = 0; nt < 2; ++nt) {
        int slot = kt_f * 4 + wn * 2 + nt;
        bh[nt] = *(const bf16x8*)(&Bs[0][slot * 512 + l8]);
        bl[nt] = *(const bf16x8*)(&Bs[1][slot * 512 + l8]);
      }
#pragma unroll
      for (int mt = 0; mt < 2; ++mt)
#pragma unroll
        for (int nt = 0; nt < 2; ++nt) {
          acc[mt][nt] = __builtin_amdgcn_mfma_f32_16x16x32_bf16(ah[mt], bh[nt], acc[mt][nt], 0, 0, 0);
          acc[mt][nt] = __builtin_amdgcn_mfma_f32_16x16x32_bf16(al[mt], bh[nt], acc[mt][nt], 0, 0, 0);
          acc[mt][nt] = __builtin_amdgcn_mfma_f32_16x16x32_bf16(ah[mt], bl[nt], acc[mt][nt], 0, 0, 0);
        }
    }
    __syncthreads();
  }
  // C/D layout: col = lane&15, row = quad*4 + reg
#pragma unroll
  for (int mt = 0; mt < 2; ++mt)
#pragma unroll
    for (int nt = 0; nt < 2; ++nt) {
      int mbase = m0 + wm * 32 + mt * 16 + quad * 4;
      int n = n0 + wn * 32 + nt * 16 + mrow;
#pragma unroll
      for (int r = 0; r < 4; ++r) {
        int m = mbase + r;
        float v = acc[mt][nt][r];
        u16 h = f2b(v);
        if (wmode == 0) {
          u16 l = f2b(v - b2f(h));
          size_t ia = pidx(m, n), ib = pidx(n, m);
          C[ia] = h;
          C[MAT + ia] = l;
          C[2 * MAT + ib] = h;
          C[3 * MAT + ib] = l;
        } else {
          C[pidx(m, n)] = h;
        }
      }
    }
}

// ---- parallel phase: out[:, z, :] = W_{z>>4} @ K^{(z&15)+1}, plain bf16.
// 128x128 tile, A direct from global (packed), B staged, KB=64 groups.
__global__ __launch_bounds__(256) void gemm_out(const u16* __restrict__ Wb,
                                                const u16* __restrict__ PT0,
                                                float* __restrict__ out) {
  __shared__ u16 Bs[16 * 512];  // 16KB
  int z = blockIdx.z;
  const u16* A = Wb + (size_t)(z >> 4) * WSLOT;
  const u16* Bt = PT0 + (size_t)(z & 15) * SLOT;
  int tid = threadIdx.x;
  int m0 = blockIdx.y * 128, n0 = blockIdx.x * 128;
  int wv = tid >> 6, lane = tid & 63;
  int wm = wv >> 1, wn = wv & 1, mrow = lane & 15, quad = lane >> 4;
  int l8 = lane * 8;
  int mchunk0 = (m0 >> 4) + wm * 4;
  int nchunk0 = n0 >> 4;
  f32x4 acc[4][4] = {};
  for (int g = 0; g < 8; ++g) {
#pragma unroll
    for (int i = 0; i < 4; ++i) {
      int id = wv * 4 + i;  // 0..15
      int kt_f = id >> 3, nt_loc = id & 7;
      const u16* src = Bt + (size_t)((nchunk0 + nt_loc) * 16 + g * 2 + kt_f) * 512 + l8;
      gll16(src, &Bs[(kt_f * 8 + nt_loc) * 512]);
    }
    __syncthreads();
#pragma unroll
    for (int kt_f = 0; kt_f < 2; ++kt_f) {
      int kt = g * 2 + kt_f;
      bf16x8 a[4], b[4];
#pragma unroll
      for (int mt = 0; mt < 4; ++mt)
        a[mt] = *(const bf16x8*)(A + (size_t)((mchunk0 + mt) * 16 + kt) * 512 + l8);
#pragma unroll
      for (int nt = 0; nt < 4; ++nt)
        b[nt] = *(const bf16x8*)(&Bs[(kt_f * 8 + wn * 4 + nt) * 512 + l8]);
#pragma unroll
      for (int mt = 0; mt < 4; ++mt)
#pragma unroll
        for (int nt = 0; nt < 4; ++nt)
          acc[mt][nt] = __builtin_amdgcn_mfma_f32_16x16x32_bf16(a[mt], b[nt], acc[mt][nt], 0, 0, 0);
    }
    __syncthreads();
  }
#pragma unroll
  for (int mt = 0; mt < 4; ++mt)
#pragma unroll
    for (int nt = 0; nt < 4; ++nt) {
      int gb = m0 + wm * 64 + mt * 16 + quad * 4;
      int gd = n0 + wn * 64 + nt * 16 + mrow;
#pragma unroll
      for (int r = 0; r < 4; ++r)
        out[((size_t)(gb + r) * 256 + z) * 512 + gd] = acc[mt][nt][r];
    }
}

extern "C" void kernel_launch(void* const* d_in, const int* in_sizes, int n_in,
                              void* d_out, int out_size, void* d_ws, size_t ws_size,
                              hipStream_t stream) {
  const float* z0 = (const float*)d_in[0];
  const float* Kc = (const float*)d_in[1];
  float* out = (float*)d_out;
  // ws layout (u16): W[16*WSLOT] | z0lo[WSLOT] | P[30*SLOT]
  u16* W = (u16*)d_ws;
  u16* z0l = W + 16 * WSLOT;
  u16* P = z0l + WSLOT;
  auto S = [&](int s) { return P + (size_t)s * SLOT; };  // 0..15 = K^{s+1}; 16..29 = K^{16(s-14)}
  dim3 blk(256);

  prep_kernel<<<96, blk, 0, stream>>>(Kc, z0, P, W, z0l);
  // small powers: K^2; {K^3,K^4}; {K^5..8}; {K^9..16}
  gemm_split<<<dim3(8, 8, 1), blk, 0, stream>>>(S(0), S(0) + MAT, 0, S(0) + 2 * MAT, 0, S(1), 0, 0);
  gemm_split<<<dim3(8, 8, 2), blk, 0, stream>>>(S(0), S(0) + MAT, SLOT, S(1) + 2 * MAT, 0, S(2), SLOT, 0);
  gemm_split<<<dim3(8, 8, 4), blk, 0, stream>>>(S(0), S(0) + MAT, SLOT, S(3) + 2 * MAT, 0, S(4), SLOT, 0);
  gemm_split<<<dim3(8, 8, 8), blk, 0, stream>>>(S(0), S(0) + MAT, SLOT, S(7) + 2 * MAT, 0, S(8), SLOT, 0);
  // big powers: K^32; {K^48,K^64}; {K^80..K^128}; {K^144..K^240}
  gemm_split<<<dim3(8, 8, 1), blk, 0, stream>>>(S(15), S(15) + MAT, 0, S(15) + 2 * MAT, 0, S(16), 0, 0);
  gemm_split<<<dim3(8, 8, 2), blk, 0, stream>>>(S(16), S(16) + MAT, 0, S(15) + 2 * MAT, SLOT, S(17), SLOT, 0);
  gemm_split<<<dim3(8, 8, 4), blk, 0, stream>>>(S(18), S(18) + MAT, 0, S(15) + 2 * MAT, SLOT, S(19), SLOT, 0);
  gemm_split<<<dim3(8, 8, 7), blk, 0, stream>>>(S(22), S(22) + MAT, 0, S(15) + 2 * MAT, SLOT, S(23), SLOT, 0);
  // w_j = z0 @ K^{16j}, j=1..15
  gemm_split<<<dim3(8, 4, 15), blk, 0, stream>>>(W, z0l, 0, S(15) + 2 * MAT, SLOT, W + WSLOT, WSLOT, 1);
  // parallel phase
  gemm_out<<<dim3(4, 2, 256), blk, 0, stream>>>(W, P + 2 * MAT, out);
}

// Round 3
// 261.919 us; speedup vs baseline: 1.1673x; 1.1673x over previous
//
#include <hip/hip_runtime.h>

// z_{t+1} = z_t @ K, T=256, B=256, D=512. out[b,t,d] = (z0 @ K^{t+1})[b,d], fp32.
//
// Chunked matrix powers, c=16 (ladder depth 8, bf16x3 split precision), then a
// fully parallel phase: out[16j+i-1] = w_j @ K^i (plain bf16).
//
// ALL intermediates are fragment-packed: 1KB chunks holding exactly what 64
// lanes of one 16x16x32 MFMA fragment read (elem = chunk*512 + lane*8 + j).
// A-operands load straight from global (coalesced dwordx4); B panels are
// CONTIGUOUS in global -> staged as consecutive 1KB gll16's, whole K=512 panel
// at once -> ONE barrier per K-loop, zero further syncs.
// Slot layout (u16): [Apk-hi | Apk-lo | Bpk-hi | Bpk-lo], Bpk(M) = Apk(M^T).

typedef unsigned short u16;
typedef unsigned int u32;
typedef __bf16 bf16x8 __attribute__((ext_vector_type(8)));
typedef float f32x4 __attribute__((ext_vector_type(4)));
typedef u16 u16x4 __attribute__((ext_vector_type(4)));
typedef u16 u16x8 __attribute__((ext_vector_type(8)));

#define MAT 262144    /* 512*512 elems */
#define SLOT 1048576  /* 4*MAT u16 per power slot */
#define WSLOT 131072  /* 256*512 */

__device__ __forceinline__ u16 f2b(float f) {  // fp32 -> bf16 (RNE)
  u32 x = __float_as_uint(f);
  return (u16)((x + 0x7fffu + ((x >> 16) & 1u)) >> 16);
}
__device__ __forceinline__ float b2f(u16 u) { return __uint_as_float(((u32)u) << 16); }

// fragment-packed index for element (r, k), K-dim = 512
__device__ __forceinline__ size_t pidx(int r, int k) {
  return (size_t)(((r >> 4) * 16 + (k >> 5)) * 512 + ((k >> 3) & 3) * 128 + (r & 15) * 8 + (k & 7));
}

__device__ __forceinline__ void gll16(const void* g, void* l) {
  __builtin_amdgcn_global_load_lds((__attribute__((address_space(1))) void*)(void*)g,
                                   (__attribute__((address_space(3))) void*)l, 16, 0, 0);
}

// ---- prep: pack K into slot0 (4 forms); split z0 -> W0(Apk-hi) + z0lo(Apk-lo) ----
__global__ __launch_bounds__(256) void prep_kernel(const float* __restrict__ Kc,
                                                   const float* __restrict__ z0,
                                                   u16* __restrict__ P,
                                                   u16* __restrict__ W0,
                                                   u16* __restrict__ z0lo) {
  int tid = threadIdx.x, b = blockIdx.x;
  if (b < 64) {
    int r0 = (b >> 3) * 64, c0b = (b & 7) * 64;
#pragma unroll
    for (int q = 0; q < 2; ++q) {
      int g = q * 256 + tid;            // 512 groups: 64 rows x 8 col-groups
      int r = r0 + (g >> 3), c0 = c0b + (g & 7) * 8;
      float4 v0 = *(const float4*)(Kc + (size_t)r * 512 + c0);
      float4 v1 = *(const float4*)(Kc + (size_t)r * 512 + c0 + 4);
      float v[8] = {v0.x, v0.y, v0.z, v0.w, v1.x, v1.y, v1.z, v1.w};
      u16x8 h8, l8v;
#pragma unroll
      for (int j = 0; j < 8; ++j) {
        u16 h = f2b(v[j]);
        h8[j] = h;
        l8v[j] = f2b(v[j] - b2f(h));
        size_t ib = pidx(c0 + j, r);    // transposed form, scalar
        P[2 * MAT + ib] = h;
        P[3 * MAT + ib] = l8v[j];
      }
      size_t ia = pidx(r, c0);          // row form, contiguous 8 -> 16B stores
      *(u16x8*)(P + ia) = h8;
      *(u16x8*)(P + MAT + ia) = l8v;
    }
  } else {
    int idb = b - 64;  // 16 blocks x 4 iters x 256 threads x 8 elems = 131072
#pragma unroll
    for (int q = 0; q < 4; ++q) {
      int g = (idb * 4 + q) * 256 + tid;
      int r = g >> 6, c0 = (g & 63) * 8;
      float4 v0 = *(const float4*)(z0 + (size_t)r * 512 + c0);
      float4 v1 = *(const float4*)(z0 + (size_t)r * 512 + c0 + 4);
      float v[8] = {v0.x, v0.y, v0.z, v0.w, v1.x, v1.y, v1.z, v1.w};
      u16x8 h8, l8v;
#pragma unroll
      for (int j = 0; j < 8; ++j) {
        u16 h = f2b(v[j]);
        h8[j] = h;
        l8v[j] = f2b(v[j] - b2f(h));
      }
      size_t ia = pidx(r, c0);
      *(u16x8*)(W0 + ia) = h8;
      *(u16x8*)(z0lo + ia) = l8v;
    }
  }
}

// ---- ladder GEMM: C[M,512] = A @ B, bf16x3. 64x32 tile, whole-K panel staged,
// ONE barrier. A hi/lo direct from global; B hi/lo panel = 64KB LDS.
// wmode 0: write full 4-form slot; wmode 1: Apk-hi only (W slot).
__global__ __launch_bounds__(256, 2) void gemm_split(
    const u16* __restrict__ A0h, const u16* __restrict__ A0l, long Astr,
    const u16* __restrict__ B0h, long Bstr,
    u16* __restrict__ C0, long Cstr, int wmode) {
  __shared__ u16 Bs[32768];  // [hi 32 chunks | lo 32 chunks] = 64KB
  int z = blockIdx.z;
  const u16* Ah = A0h + (size_t)z * Astr;
  const u16* Al = A0l + (size_t)z * Astr;
  const u16* Bh = B0h + (size_t)z * Bstr;
  const u16* Bl = Bh + MAT;
  u16* C = C0 + (size_t)z * Cstr;
  int tid = threadIdx.x;
  int m0 = blockIdx.y * 64, n0 = blockIdx.x * 32;
  int wv = tid >> 6, lane = tid & 63;
  int mrow = lane & 15, quad = lane >> 4;
  int l8 = lane * 8;
  int nchunk0 = n0 >> 4;                 // 2 nchunks x 16 kchunks = 32 chunks/form
  const u16* ph = Bh + (size_t)nchunk0 * 16 * 512;  // contiguous 32KB panel
  const u16* pl = Bl + (size_t)nchunk0 * 16 * 512;
#pragma unroll
  for (int i = 0; i < 8; ++i) {          // wave wv stages chunks wv*8+i (hi & lo)
    int ch = wv * 8 + i;
    gll16(ph + (size_t)ch * 512 + l8, Bs + ch * 512);
    gll16(pl + (size_t)ch * 512 + l8, Bs + 16384 + ch * 512);
  }
  __syncthreads();                       // the ONLY barrier
  int mc = (m0 >> 4) + wv;               // wave-tile 16x32 (4-way m-split)
  f32x4 acc[2] = {};
#pragma unroll 4
  for (int kt = 0; kt < 16; ++kt) {
    size_t co = (size_t)(mc * 16 + kt) * 512 + l8;
    bf16x8 ah = *(const bf16x8*)(Ah + co);
    bf16x8 al = *(const bf16x8*)(Al + co);
#pragma unroll
    for (int nt = 0; nt < 2; ++nt) {
      bf16x8 bh = *(const bf16x8*)(Bs + (nt * 16 + kt) * 512 + l8);
      bf16x8 bl = *(const bf16x8*)(Bs + 16384 + (nt * 16 + kt) * 512 + l8);
      acc[nt] = __builtin_amdgcn_mfma_f32_16x16x32_bf16(ah, bh, acc[nt], 0, 0, 0);
      acc[nt] = __builtin_amdgcn_mfma_f32_16x16x32_bf16(al, bh, acc[nt], 0, 0, 0);
      acc[nt] = __builtin_amdgcn_mfma_f32_16x16x32_bf16(ah, bl, acc[nt], 0, 0, 0);
    }
  }
  // C/D layout: col = lane&15, row = quad*4 + reg
  int mbase = m0 + wv * 16 + quad * 4;
#pragma unroll
  for (int nt = 0; nt < 2; ++nt) {
    int n = n0 + nt * 16 + mrow;
    if (wmode == 0) {
      u16x4 h4, l4;
#pragma unroll
      for (int r = 0; r < 4; ++r) {
        float v = acc[nt][r];
        u16 h = f2b(v), l = f2b(v - b2f(h));
        size_t ia = pidx(mbase + r, n);
        C[ia] = h;
        C[MAT + ia] = l;
        h4[r] = h;
        l4[r] = l;
      }
      size_t ib = pidx(n, mbase);        // 4 consecutive u16 (m&7 = quad&1*4 + r)
      *(u16x4*)(C + 2 * MAT + ib) = h4;
      *(u16x4*)(C + 3 * MAT + ib) = l4;
    } else {
#pragma unroll
      for (int r = 0; r < 4; ++r) C[pidx(mbase + r, n)] = f2b(acc[nt][r]);
    }
  }
}

// ---- parallel phase: out[:, z, :] = W_{z>>4} @ K^{(z&15)+1}, plain bf16.
// 256x64 tile, whole-K panel (64KB) staged once, ONE barrier, 4-way m-split.
__global__ __launch_bounds__(256, 2) void gemm_out(const u16* __restrict__ Wb,
                                                   const u16* __restrict__ PT0,
                                                   float* __restrict__ out) {
  __shared__ u16 Bs[32768];  // 4 nchunks x 16 kchunks = 64 chunks = 64KB
  int z = blockIdx.z;
  const u16* A = Wb + (size_t)(z >> 4) * WSLOT;
  const u16* Bt = PT0 + (size_t)(z & 15) * SLOT;
  int tid = threadIdx.x;
  int n0 = blockIdx.x * 64;
  int wv = tid >> 6, lane = tid & 63;
  int mrow = lane & 15, quad = lane >> 4;
  int l8 = lane * 8;
  const u16* pb = Bt + (size_t)(n0 >> 4) * 16 * 512;  // contiguous 64KB panel
#pragma unroll
  for (int i = 0; i < 16; ++i) {
    int ch = wv * 16 + i;
    gll16(pb + (size_t)ch * 512 + l8, Bs + ch * 512);
  }
  __syncthreads();                       // the ONLY barrier
  int mc0 = wv * 4;                      // wave-tile 64x64
  f32x4 acc[4][4] = {};
#pragma unroll 4
  for (int kt = 0; kt < 16; ++kt) {
    bf16x8 a[4], b[4];
#pragma unroll
    for (int mt = 0; mt < 4; ++mt)
      a[mt] = *(const bf16x8*)(A + (size_t)((mc0 + mt) * 16 + kt) * 512 + l8);
#pragma unroll
    for (int nt = 0; nt < 4; ++nt)
      b[nt] = *(const bf16x8*)(Bs + (nt * 16 + kt) * 512 + l8);
#pragma unroll
    for (int mt = 0; mt < 4; ++mt)
#pragma unroll
      for (int nt = 0; nt < 4; ++nt)
        acc[mt][nt] = __builtin_amdgcn_mfma_f32_16x16x32_bf16(a[mt], b[nt], acc[mt][nt], 0, 0, 0);
  }
#pragma unroll
  for (int mt = 0; mt < 4; ++mt)
#pragma unroll
    for (int nt = 0; nt < 4; ++nt) {
      int gb = wv * 64 + mt * 16 + quad * 4;
      int gd = n0 + nt * 16 + mrow;
#pragma unroll
      for (int r = 0; r < 4; ++r)
        out[((size_t)(gb + r) * 256 + z) * 512 + gd] = acc[mt][nt][r];
    }
}

extern "C" void kernel_launch(void* const* d_in, const int* in_sizes, int n_in,
                              void* d_out, int out_size, void* d_ws, size_t ws_size,
                              hipStream_t stream) {
  const float* z0 = (const float*)d_in[0];
  const float* Kc = (const float*)d_in[1];
  float* out = (float*)d_out;
  // ws layout (u16): W[16*WSLOT] | z0lo[WSLOT] | P[30*SLOT]
  u16* W = (u16*)d_ws;
  u16* z0l = W + 16 * WSLOT;
  u16* P = z0l + WSLOT;
  auto S = [&](int s) { return P + (size_t)s * SLOT; };  // 0..15 = K^{s+1}; 16..29 = K^{16(s-14)}
  dim3 blk(256);

  prep_kernel<<<80, blk, 0, stream>>>(Kc, z0, P, W, z0l);
  // small powers: K^2; {K^3,K^4}; {K^5..8}; {K^9..16}
  gemm_split<<<dim3(16, 8, 1), blk, 0, stream>>>(S(0), S(0) + MAT, 0, S(0) + 2 * MAT, 0, S(1), 0, 0);
  gemm_split<<<dim3(16, 8, 2), blk, 0, stream>>>(S(0), S(0) + MAT, SLOT, S(1) + 2 * MAT, 0, S(2), SLOT, 0);
  gemm_split<<<dim3(16, 8, 4), blk, 0, stream>>>(S(0), S(0) + MAT, SLOT, S(3) + 2 * MAT, 0, S(4), SLOT, 0);
  gemm_split<<<dim3(16, 8, 8), blk, 0, stream>>>(S(0), S(0) + MAT, SLOT, S(7) + 2 * MAT, 0, S(8), SLOT, 0);
  // big powers: K^32; {K^48,K^64}; {K^80..K^128}; {K^144..K^240}
  gemm_split<<<dim3(16, 8, 1), blk, 0, stream>>>(S(15), S(15) + MAT, 0, S(15) + 2 * MAT, 0, S(16), 0, 0);
  gemm_split<<<dim3(16, 8, 2), blk, 0, stream>>>(S(16), S(16) + MAT, 0, S(15) + 2 * MAT, SLOT, S(17), SLOT, 0);
  gemm_split<<<dim3(16, 8, 4), blk, 0, stream>>>(S(18), S(18) + MAT, 0, S(15) + 2 * MAT, SLOT, S(19), SLOT, 0);
  gemm_split<<<dim3(16, 8, 7), blk, 0, stream>>>(S(22), S(22) + MAT, 0, S(15) + 2 * MAT, SLOT, S(23), SLOT, 0);
  // w_j = z0 @ K^{16j}, j=1..15
  gemm_split<<<dim3(16, 4, 15), blk, 0, stream>>>(W, z0l, 0, S(15) + 2 * MAT, SLOT, W + WSLOT, WSLOT, 1);
  // parallel phase: 2048 WGs, one per (n-tile, t)
  gemm_out<<<dim3(8, 1, 256), blk, 0, stream>>>(W, P + 2 * MAT, out);
}